// Round 1
// baseline (486.370 us; speedup 1.0000x reference)
//
#include <hip/hip_runtime.h>

// ---------------------------------------------------------------------------
// cross_entropy_with_hnm_for_one_class_detection
//
// 3 scales, each: softmax-CE with hard-negative mining (needs k-th order
// statistic of neg_prob over N=B*H*W) + masked bbox MSE. Output: 3 floats.
//
// Sort replaced by exact 2-level 16-bit radix select on float bits
// (all values >= 0 so bit order == numeric order).
// ---------------------------------------------------------------------------

namespace {
constexpr int BATCH = 32;
constexpr int HW0 = 160 * 160;   // 25600
constexpr int HW1 = 80 * 80;     // 6400
constexpr int HW2 = 40 * 40;     // 1600
constexpr int N0 = BATCH * HW0;  // 819200
constexpr int N1 = BATCH * HW1;  // 204800
constexpr int N2 = BATCH * HW2;  // 51200
constexpr int NT = N0 + N1 + N2; // 1075200
constexpr int HISTN = 65536;

struct ScaleScal {
  unsigned int pos_cnt;
  unsigned int neg_cnt;
  unsigned int bin_hi;
  unsigned int rank;
  unsigned int thr_bits;
  unsigned int pad0, pad1, pad2;
  double sum_pos_ce;
  double sum_diff2;
  double sum_neg_ce;
  double pad3;
};  // 64 bytes
}  // namespace

// ---------------- pass 1: softmax, counts, pos-CE, bbox, hi histogram -------
template <int HW, int N>
__device__ void pass1_body(const float* __restrict__ sc,
                           const float* __restrict__ bb,
                           const float* __restrict__ gl,
                           unsigned int* __restrict__ hist,
                           ScaleScal* __restrict__ ss,
                           float* __restrict__ npv,
                           float* __restrict__ cev) {
  const int tid = threadIdx.x;
  double posce = 0.0, diff2 = 0.0;
  unsigned int pcnt = 0, ncnt = 0;
  const int stride = gridDim.x * blockDim.x;
  for (int p = blockIdx.x * blockDim.x + tid; p < N; p += stride) {
    const int b = p / HW;
    const int hw = p - b * HW;
    const float* scp = sc + (size_t)b * 2 * HW + hw;
    const float s0 = scp[0];
    const float s1 = scp[HW];
    const float m = fmaxf(s0, s1);
    const float e0 = expf(s0 - m);
    const float e1 = expf(s1 - m);
    const float esum = e0 + e1;
    const float sm1 = e1 / esum;
    const float lse = logf(esum);
    const float ls0 = (s0 - m) - lse;
    const float ls1 = (s1 - m) - lse;
    const float* glp = gl + (size_t)b * 6 * HW + hw;
    const float l0 = glp[0];
    const float l1 = glp[HW];
    const bool pos = l0 > 0.5f;
    const bool neg = l1 > 0.5f;
    const float np = neg ? sm1 : 0.0f;
    const float ce = neg ? (-l1 * ls1) : 0.0f;
    npv[p] = np;
    cev[p] = ce;
    const unsigned int bits = __float_as_uint(np);
    atomicAdd(&hist[bits >> 16], 1u);
    if (neg) ncnt++;
    if (pos) {
      pcnt++;
      posce += (double)(-l0 * ls0);
      const float* bbp = bb + (size_t)b * 4 * HW + hw;
      float acc = 0.0f;
#pragma unroll
      for (int c = 0; c < 4; ++c) {
        const float t = glp[(2 + c) * HW];
        const float pv = bbp[c * HW];
        const float d = t - pv;
        acc += d * d;
      }
      diff2 += (double)acc;
    }
  }
  __shared__ double sd[256];
  __shared__ unsigned int su[256];
  sd[tid] = posce;
  su[tid] = pcnt;
  __syncthreads();
  for (int o = 128; o > 0; o >>= 1) {
    if (tid < o) { sd[tid] += sd[tid + o]; su[tid] += su[tid + o]; }
    __syncthreads();
  }
  if (tid == 0) {
    if (sd[0] != 0.0) atomicAdd(&ss->sum_pos_ce, sd[0]);
    if (su[0]) atomicAdd(&ss->pos_cnt, su[0]);
  }
  __syncthreads();
  sd[tid] = diff2;
  su[tid] = ncnt;
  __syncthreads();
  for (int o = 128; o > 0; o >>= 1) {
    if (tid < o) { sd[tid] += sd[tid + o]; su[tid] += su[tid + o]; }
    __syncthreads();
  }
  if (tid == 0) {
    if (sd[0] != 0.0) atomicAdd(&ss->sum_diff2, sd[0]);
    if (su[0]) atomicAdd(&ss->neg_cnt, su[0]);
  }
}

__global__ __launch_bounds__(256) void k_pass1(
    const float* sc0, const float* bb0, const float* gl0,
    const float* sc1, const float* bb1, const float* gl1,
    const float* sc2, const float* bb2, const float* gl2,
    unsigned int* hist_hi, ScaleScal* scal, float* npv, float* cev) {
  const int s = blockIdx.y;
  if (s == 0)
    pass1_body<HW0, N0>(sc0, bb0, gl0, hist_hi, scal, npv, cev);
  else if (s == 1)
    pass1_body<HW1, N1>(sc1, bb1, gl1, hist_hi + HISTN, scal + 1, npv + N0, cev + N0);
  else
    pass1_body<HW2, N2>(sc2, bb2, gl2, hist_hi + 2 * HISTN, scal + 2,
                        npv + N0 + N1, cev + N0 + N1);
}

// ---------------- pass 2: scan hi histogram, find bin + residual rank -------
__global__ __launch_bounds__(256) void k_scan_hi(const unsigned int* __restrict__ hist_hi,
                                                 ScaleScal* scal) {
  const int s = blockIdx.x;
  const unsigned int* h = hist_hi + s * HISTN;
  ScaleScal* ss = scal + s;
  __shared__ unsigned int csum[256];
  const int tid = threadIdx.x;
  unsigned int acc = 0;
  for (int i = 0; i < 256; ++i) acc += h[tid * 256 + i];
  csum[tid] = acc;
  __syncthreads();
  if (tid == 0) {
    const unsigned int pos = ss->pos_cnt;
    const unsigned int neg = ss->neg_cnt;
    const unsigned long long k10 = 10ull * (unsigned long long)pos;
    const unsigned int k =
        (k10 < (unsigned long long)neg) ? (unsigned int)k10 : neg;
    unsigned int run = 0;
    int chunk = 255;
    for (int t = 0; t < 256; ++t) {
      if (run + csum[t] > k) { chunk = t; break; }
      run += csum[t];
    }
    unsigned int bn_sel = (unsigned int)(chunk * 256 + 255);
    unsigned int r = 0;
    for (int bn = chunk * 256; bn < chunk * 256 + 256; ++bn) {
      const unsigned int c = h[bn];
      if (run + c > k) { bn_sel = (unsigned int)bn; r = k - run; break; }
      run += c;
    }
    ss->bin_hi = bn_sel;
    ss->rank = r;
  }
}

// ---------------- pass 3: low-16-bit histogram of selected hi bin -----------
__global__ __launch_bounds__(256) void k_hist_lo(const float* __restrict__ npv,
                                                 const ScaleScal* __restrict__ scal,
                                                 unsigned int* __restrict__ hist_lo) {
  const int s = blockIdx.y;
  const int Ns = (s == 0) ? N0 : (s == 1) ? N1 : N2;
  const int base = (s == 0) ? 0 : (s == 1) ? N0 : (N0 + N1);
  const unsigned int bhi = scal[s].bin_hi;
  unsigned int* h = hist_lo + s * HISTN;
  const int stride = gridDim.x * blockDim.x;
  for (int p = blockIdx.x * blockDim.x + threadIdx.x; p < Ns; p += stride) {
    const unsigned int bits = __float_as_uint(npv[base + p]);
    if ((bits >> 16) == bhi) atomicAdd(&h[bits & 0xFFFFu], 1u);
  }
}

// ---------------- pass 4: scan lo histogram -> exact threshold --------------
__global__ __launch_bounds__(256) void k_scan_lo(const unsigned int* __restrict__ hist_lo,
                                                 ScaleScal* scal) {
  const int s = blockIdx.x;
  const unsigned int* h = hist_lo + s * HISTN;
  ScaleScal* ss = scal + s;
  __shared__ unsigned int csum[256];
  const int tid = threadIdx.x;
  unsigned int acc = 0;
  for (int i = 0; i < 256; ++i) acc += h[tid * 256 + i];
  csum[tid] = acc;
  __syncthreads();
  if (tid == 0) {
    const unsigned int k = ss->rank;
    unsigned int run = 0;
    int chunk = 255;
    for (int t = 0; t < 256; ++t) {
      if (run + csum[t] > k) { chunk = t; break; }
      run += csum[t];
    }
    unsigned int lo = (unsigned int)(chunk * 256 + 255);
    for (int bn = chunk * 256; bn < chunk * 256 + 256; ++bn) {
      const unsigned int c = h[bn];
      if (run + c > k) { lo = (unsigned int)bn; break; }
      run += c;
    }
    ss->thr_bits = (ss->bin_hi << 16) | lo;
  }
}

// ---------------- pass 5: sum CE of selected negatives ----------------------
__global__ __launch_bounds__(256) void k_negce(const float* __restrict__ npv,
                                               const float* __restrict__ cev,
                                               ScaleScal* scal) {
  const int s = blockIdx.y;
  const int Ns = (s == 0) ? N0 : (s == 1) ? N1 : N2;
  const int base = (s == 0) ? 0 : (s == 1) ? N0 : (N0 + N1);
  const float thr = __uint_as_float(scal[s].thr_bits);
  double acc = 0.0;
  const int stride = gridDim.x * blockDim.x;
  for (int p = blockIdx.x * blockDim.x + threadIdx.x; p < Ns; p += stride) {
    const float v = npv[base + p];
    if (v <= thr) acc += (double)cev[base + p];
  }
  __shared__ double sd[256];
  const int tid = threadIdx.x;
  sd[tid] = acc;
  __syncthreads();
  for (int o = 128; o > 0; o >>= 1) {
    if (tid < o) sd[tid] += sd[tid + o];
    __syncthreads();
  }
  if (tid == 0 && sd[0] != 0.0) atomicAdd(&scal[s].sum_neg_ce, sd[0]);
}

// ---------------- pass 6: finalize ------------------------------------------
__global__ void k_final(const ScaleScal* __restrict__ scal, float* __restrict__ out) {
  const int s = threadIdx.x;
  if (s < 3) {
    const ScaleScal& ss = scal[s];
    const double Ns = (s == 0) ? (double)N0 : (s == 1) ? (double)N1 : (double)N2;
    const double W = (s == 0) ? 160.0 : (s == 1) ? 80.0 : 40.0;
    const double ls = (ss.sum_pos_ce + ss.sum_neg_ce) / (2.0 * Ns);
    const double lb = (ss.sum_diff2 / W) / (4.0 * (double)ss.pos_cnt);
    out[s] = (float)(ls + lb);
  }
}

extern "C" void kernel_launch(void* const* d_in, const int* in_sizes, int n_in,
                              void* d_out, int out_size, void* d_ws, size_t ws_size,
                              hipStream_t stream) {
  const float* sc0 = (const float*)d_in[0];
  const float* bb0 = (const float*)d_in[1];
  const float* gl0 = (const float*)d_in[3];
  const float* sc1 = (const float*)d_in[4];
  const float* bb1 = (const float*)d_in[5];
  const float* gl1 = (const float*)d_in[7];
  const float* sc2 = (const float*)d_in[8];
  const float* bb2 = (const float*)d_in[9];
  const float* gl2 = (const float*)d_in[11];

  char* ws = (char*)d_ws;
  unsigned int* hist_hi = (unsigned int*)ws;
  unsigned int* hist_lo = hist_hi + 3 * HISTN;
  ScaleScal* scal = (ScaleScal*)(hist_lo + 3 * HISTN);
  size_t zbytes = (size_t)3 * HISTN * 4 * 2 + 3 * sizeof(ScaleScal);
  zbytes = (zbytes + 255) & ~(size_t)255;
  float* npv = (float*)(ws + zbytes);
  float* cev = npv + NT;

  // zero histograms + scalar accumulators (harness poisons ws with 0xAA)
  hipMemsetAsync(d_ws, 0, zbytes, stream);

  const dim3 blk(256);
  const dim3 g1(1280, 3);
  k_pass1<<<g1, blk, 0, stream>>>(sc0, bb0, gl0, sc1, bb1, gl1, sc2, bb2, gl2,
                                  hist_hi, scal, npv, cev);
  k_scan_hi<<<dim3(3), blk, 0, stream>>>(hist_hi, scal);
  k_hist_lo<<<g1, blk, 0, stream>>>(npv, scal, hist_lo);
  k_scan_lo<<<dim3(3), blk, 0, stream>>>(hist_lo, scal);
  k_negce<<<g1, blk, 0, stream>>>(npv, cev, scal);
  k_final<<<1, 64, 0, stream>>>(scal, (float*)d_out);
}

// Round 2
// 108.788 us; speedup vs baseline: 4.4708x; 4.4708x over previous
//
#include <hip/hip_runtime.h>

// ---------------------------------------------------------------------------
// cross_entropy_with_hnm_for_one_class_detection
//
// 3 scales, each: softmax-CE with hard-negative mining (k-th order statistic
// of neg_prob over N=B*H*W) + masked bbox MSE. Output: 3 floats.
//
// k-th order statistic via exact 3-level radix select (12+12+8 bits) on the
// float bit pattern (all values >= 0 so bit order == numeric order).
// Histograms are LDS-privatized (global same-address atomic serialization
// was the R1 bottleneck: 440us @ 0.9% VALUBusy). Bin-selection scans are
// fused as redundant per-block prologues of the next pass.
// ---------------------------------------------------------------------------

namespace {
constexpr int BATCH = 32;
constexpr int HW0 = 160 * 160;   // 25600
constexpr int HW1 = 80 * 80;     // 6400
constexpr int HW2 = 40 * 40;     // 1600
constexpr int N0 = BATCH * HW0;  // 819200
constexpr int N1 = BATCH * HW1;  // 204800
constexpr int N2 = BATCH * HW2;  // 51200
constexpr int NT = N0 + N1 + N2; // 1075200

constexpr int L1BINS = 4096;  // bits [31:20]
constexpr int L2BINS = 4096;  // bits [19:8]
constexpr int L3BINS = 256;   // bits [7:0]

// flat grid partition across the 3 scales (proportional to N)
constexpr int B0 = 832, B1 = 208, B2 = 52;
constexpr int NBLK = B0 + B1 + B2;  // 1092

struct ScaleScal {
  unsigned int pos_cnt;
  unsigned int neg_cnt;
  unsigned int pad0, pad1;
  double sum_pos_ce;
  double sum_diff2;
  double sum_neg_ce;
  double pad2;
};  // 48 bytes

__device__ inline void scale_of(int blk, int& s, int& rel, int& nb, int& N,
                                int& base) {
  if (blk < B0) {
    s = 0; rel = blk; nb = B0; N = N0; base = 0;
  } else if (blk < B0 + B1) {
    s = 1; rel = blk - B0; nb = B1; N = N1; base = N0;
  } else {
    s = 2; rel = blk - B0 - B1; nb = B2; N = N2; base = N0 + N1;
  }
}

__device__ inline unsigned int hnm_k(const ScaleScal& ss) {
  const unsigned long long k10 = 10ull * (unsigned long long)ss.pos_cnt;
  return (k10 < (unsigned long long)ss.neg_cnt) ? (unsigned int)k10
                                                : ss.neg_cnt;
}

// Block-wide: find bin containing 0-based rank k in ascending bin order.
// Writes *sel_bin / *sel_rank (shared) ; all threads see result after return.
__device__ void radix_scan(const unsigned int* __restrict__ h, int nbins,
                           unsigned int k, unsigned int* sel_bin,
                           unsigned int* sel_rank) {
  __shared__ unsigned int part[256];
  const int tid = threadIdx.x;
  const int per = nbins >> 8;
  unsigned int own = 0;
  for (int i = 0; i < per; ++i) own += h[tid * per + i];
  part[tid] = own;
  __syncthreads();
  // inclusive Hillis-Steele scan over 256 partials
  for (int o = 1; o < 256; o <<= 1) {
    const unsigned int add = (tid >= o) ? part[tid - o] : 0u;
    __syncthreads();
    part[tid] += add;
    __syncthreads();
  }
  const unsigned int incl = part[tid];
  const unsigned int excl = incl - own;
  if (own && k >= excl && k < incl) {  // unique winner (k < total)
    unsigned int run = excl;
    for (int i = 0; i < per; ++i) {
      const unsigned int c = h[tid * per + i];
      if (run + c > k) {
        *sel_bin = (unsigned int)(tid * per + i);
        *sel_rank = k - run;
        break;
      }
      run += c;
    }
  }
  __syncthreads();
}
}  // namespace

// ---------------- pass 1: softmax, counts, pos-CE, bbox, L1 histogram -------
template <int HW, int N>
__device__ void pass1_body(int rel, int nb, const float* __restrict__ sc,
                           const float* __restrict__ bb,
                           const float* __restrict__ gl,
                           unsigned int* __restrict__ hist,
                           ScaleScal* __restrict__ ss,
                           float* __restrict__ npv,
                           float* __restrict__ cev,
                           unsigned int* __restrict__ lh) {
  const int tid = threadIdx.x;
  for (int i = tid; i < L1BINS; i += 256) lh[i] = 0;
  __syncthreads();

  double posce = 0.0, diff2 = 0.0;
  unsigned int pcnt = 0, ncnt = 0;
  const int stride = nb * 256;
  for (int p = rel * 256 + tid; p < N; p += stride) {
    const int b = p / HW;
    const int hw = p - b * HW;
    const float* scp = sc + (size_t)b * 2 * HW + hw;
    const float s0 = scp[0];
    const float s1 = scp[HW];
    const float m = fmaxf(s0, s1);
    const float e0 = expf(s0 - m);
    const float e1 = expf(s1 - m);
    const float esum = e0 + e1;
    const float sm1 = e1 / esum;
    const float lse = logf(esum);
    const float ls0 = (s0 - m) - lse;
    const float ls1 = (s1 - m) - lse;
    const float* glp = gl + (size_t)b * 6 * HW + hw;
    const float l0 = glp[0];
    const float l1 = glp[HW];
    const bool pos = l0 > 0.5f;
    const bool neg = l1 > 0.5f;
    const float np = neg ? sm1 : 0.0f;
    const float ce = neg ? (-l1 * ls1) : 0.0f;
    npv[p] = np;
    cev[p] = ce;
    atomicAdd(&lh[__float_as_uint(np) >> 20], 1u);
    if (neg) ncnt++;
    if (pos) {
      pcnt++;
      posce += (double)(-l0 * ls0);
      const float* bbp = bb + (size_t)b * 4 * HW + hw;
      float acc = 0.0f;
#pragma unroll
      for (int c = 0; c < 4; ++c) {
        const float t = glp[(2 + c) * HW];
        const float pv = bbp[c * HW];
        const float d = t - pv;
        acc += d * d;
      }
      diff2 += (double)acc;
    }
  }
  __syncthreads();
  for (int i = tid; i < L1BINS; i += 256) {
    const unsigned int c = lh[i];
    if (c) atomicAdd(&hist[i], c);
  }

  __shared__ double sd[256];
  __shared__ unsigned int su[256];
  sd[tid] = posce;
  su[tid] = pcnt;
  __syncthreads();
  for (int o = 128; o > 0; o >>= 1) {
    if (tid < o) { sd[tid] += sd[tid + o]; su[tid] += su[tid + o]; }
    __syncthreads();
  }
  if (tid == 0) {
    if (sd[0] != 0.0) atomicAdd(&ss->sum_pos_ce, sd[0]);
    if (su[0]) atomicAdd(&ss->pos_cnt, su[0]);
  }
  __syncthreads();
  sd[tid] = diff2;
  su[tid] = ncnt;
  __syncthreads();
  for (int o = 128; o > 0; o >>= 1) {
    if (tid < o) { sd[tid] += sd[tid + o]; su[tid] += su[tid + o]; }
    __syncthreads();
  }
  if (tid == 0) {
    if (sd[0] != 0.0) atomicAdd(&ss->sum_diff2, sd[0]);
    if (su[0]) atomicAdd(&ss->neg_cnt, su[0]);
  }
}

__global__ __launch_bounds__(256) void k_pass1(
    const float* sc0, const float* bb0, const float* gl0,
    const float* sc1, const float* bb1, const float* gl1,
    const float* sc2, const float* bb2, const float* gl2,
    unsigned int* hist1, ScaleScal* scal, float* npv, float* cev) {
  __shared__ unsigned int lh[L1BINS];
  int s, rel, nb, N, base;
  scale_of(blockIdx.x, s, rel, nb, N, base);
  if (s == 0)
    pass1_body<HW0, N0>(rel, nb, sc0, bb0, gl0, hist1, scal, npv, cev, lh);
  else if (s == 1)
    pass1_body<HW1, N1>(rel, nb, sc1, bb1, gl1, hist1 + L1BINS, scal + 1,
                        npv + N0, cev + N0, lh);
  else
    pass1_body<HW2, N2>(rel, nb, sc2, bb2, gl2, hist1 + 2 * L1BINS, scal + 2,
                        npv + N0 + N1, cev + N0 + N1, lh);
}

// ---------------- pass 2: L2 histogram of selected L1 bin -------------------
__global__ __launch_bounds__(256) void k_hist2(
    const unsigned int* __restrict__ hist1, const float* __restrict__ npv,
    const ScaleScal* __restrict__ scal, unsigned int* __restrict__ hist2) {
  __shared__ unsigned int lh[L2BINS];
  __shared__ unsigned int b1, r1;
  int s, rel, nb, N, base;
  scale_of(blockIdx.x, s, rel, nb, N, base);
  radix_scan(hist1 + s * L1BINS, L1BINS, hnm_k(scal[s]), &b1, &r1);

  const int tid = threadIdx.x;
  for (int i = tid; i < L2BINS; i += 256) lh[i] = 0;
  __syncthreads();
  const unsigned int sel = b1;
  const int stride = nb * 256;
  for (int p = rel * 256 + tid; p < N; p += stride) {
    const unsigned int bits = __float_as_uint(npv[base + p]);
    if ((bits >> 20) == sel) atomicAdd(&lh[(bits >> 8) & 0xFFFu], 1u);
  }
  __syncthreads();
  unsigned int* g = hist2 + s * L2BINS;
  for (int i = tid; i < L2BINS; i += 256) {
    const unsigned int c = lh[i];
    if (c) atomicAdd(&g[i], c);
  }
}

// ---------------- pass 3: L3 histogram of selected L1+L2 bin ----------------
__global__ __launch_bounds__(256) void k_hist3(
    const unsigned int* __restrict__ hist1,
    const unsigned int* __restrict__ hist2, const float* __restrict__ npv,
    const ScaleScal* __restrict__ scal, unsigned int* __restrict__ hist3) {
  __shared__ unsigned int lh[L3BINS];
  __shared__ unsigned int b1, r1, b2, r2;
  int s, rel, nb, N, base;
  scale_of(blockIdx.x, s, rel, nb, N, base);
  radix_scan(hist1 + s * L1BINS, L1BINS, hnm_k(scal[s]), &b1, &r1);
  radix_scan(hist2 + s * L2BINS, L2BINS, r1, &b2, &r2);

  const int tid = threadIdx.x;
  for (int i = tid; i < L3BINS; i += 256) lh[i] = 0;
  __syncthreads();
  const unsigned int sel24 = (b1 << 12) | b2;  // top 24 bits
  const int stride = nb * 256;
  for (int p = rel * 256 + tid; p < N; p += stride) {
    const unsigned int bits = __float_as_uint(npv[base + p]);
    if ((bits >> 8) == sel24) atomicAdd(&lh[bits & 0xFFu], 1u);
  }
  __syncthreads();
  unsigned int* g = hist3 + s * L3BINS;
  for (int i = tid; i < L3BINS; i += 256) {
    const unsigned int c = lh[i];
    if (c) atomicAdd(&g[i], c);
  }
}

// ---------------- pass 4: threshold + sum CE of selected negatives ----------
__global__ __launch_bounds__(256) void k_negce(
    const unsigned int* __restrict__ hist1,
    const unsigned int* __restrict__ hist2,
    const unsigned int* __restrict__ hist3, const float* __restrict__ npv,
    const float* __restrict__ cev, ScaleScal* scal) {
  __shared__ unsigned int b1, r1, b2, r2, b3, r3;
  int s, rel, nb, N, base;
  scale_of(blockIdx.x, s, rel, nb, N, base);
  radix_scan(hist1 + s * L1BINS, L1BINS, hnm_k(scal[s]), &b1, &r1);
  radix_scan(hist2 + s * L2BINS, L2BINS, r1, &b2, &r2);
  radix_scan(hist3 + s * L3BINS, L3BINS, r2, &b3, &r3);

  const float thr = __uint_as_float((b1 << 20) | (b2 << 8) | b3);
  double acc = 0.0;
  const int tid = threadIdx.x;
  const int stride = nb * 256;
  for (int p = rel * 256 + tid; p < N; p += stride) {
    const float v = npv[base + p];
    if (v <= thr) acc += (double)cev[base + p];
  }
  __shared__ double sd[256];
  sd[tid] = acc;
  __syncthreads();
  for (int o = 128; o > 0; o >>= 1) {
    if (tid < o) sd[tid] += sd[tid + o];
    __syncthreads();
  }
  if (tid == 0 && sd[0] != 0.0) atomicAdd(&scal[s].sum_neg_ce, sd[0]);
}

// ---------------- pass 5: finalize ------------------------------------------
__global__ void k_final(const ScaleScal* __restrict__ scal,
                        float* __restrict__ out) {
  const int s = threadIdx.x;
  if (s < 3) {
    const ScaleScal& ss = scal[s];
    const double Ns = (s == 0) ? (double)N0 : (s == 1) ? (double)N1 : (double)N2;
    const double W = (s == 0) ? 160.0 : (s == 1) ? 80.0 : 40.0;
    const double ls = (ss.sum_pos_ce + ss.sum_neg_ce) / (2.0 * Ns);
    const double lb = (ss.sum_diff2 / W) / (4.0 * (double)ss.pos_cnt);
    out[s] = (float)(ls + lb);
  }
}

extern "C" void kernel_launch(void* const* d_in, const int* in_sizes, int n_in,
                              void* d_out, int out_size, void* d_ws,
                              size_t ws_size, hipStream_t stream) {
  const float* sc0 = (const float*)d_in[0];
  const float* bb0 = (const float*)d_in[1];
  const float* gl0 = (const float*)d_in[3];
  const float* sc1 = (const float*)d_in[4];
  const float* bb1 = (const float*)d_in[5];
  const float* gl1 = (const float*)d_in[7];
  const float* sc2 = (const float*)d_in[8];
  const float* bb2 = (const float*)d_in[9];
  const float* gl2 = (const float*)d_in[11];

  char* ws = (char*)d_ws;
  unsigned int* hist1 = (unsigned int*)ws;
  unsigned int* hist2 = hist1 + 3 * L1BINS;
  unsigned int* hist3 = hist2 + 3 * L2BINS;
  ScaleScal* scal = (ScaleScal*)(hist3 + 3 * L3BINS);
  size_t zbytes =
      (size_t)(3 * L1BINS + 3 * L2BINS + 3 * L3BINS) * 4 + 3 * sizeof(ScaleScal);
  zbytes = (zbytes + 255) & ~(size_t)255;
  float* npv = (float*)(ws + zbytes);
  float* cev = npv + NT;

  hipMemsetAsync(d_ws, 0, zbytes, stream);

  const dim3 blk(256);
  const dim3 grd(NBLK);
  k_pass1<<<grd, blk, 0, stream>>>(sc0, bb0, gl0, sc1, bb1, gl1, sc2, bb2, gl2,
                                   hist1, scal, npv, cev);
  k_hist2<<<grd, blk, 0, stream>>>(hist1, npv, scal, hist2);
  k_hist3<<<grd, blk, 0, stream>>>(hist1, hist2, npv, scal, hist3);
  k_negce<<<grd, blk, 0, stream>>>(hist1, hist2, hist3, npv, cev, scal);
  k_final<<<1, 64, 0, stream>>>(scal, (float*)d_out);
}